// Round 5
// baseline (88.687 us; speedup 1.0000x reference)
//
#include <hip/hip_runtime.h>

// MQuantileLoss: B=4096 rows, N=8192 cols fp32.
// Two-pass:
//  (1) streaming chunk sums (128 el/chunk) -> d_ws. Coalesced 1-KiB wave
//      loads, 8 independent loads in flight per wave, 8 parallel 5-level
//      xor-reduce chains after the load batch (no serial load->chain->load).
//  (2) per-(row,matrix) wave: scan 64 partials, owner lanes re-read their
//      512-B chunk and compute the reference's piecewise-linear quantile.

constexpr int NCOL  = 8192;
constexpr int CHUNK = 128;                 // elements per partial
constexpr int NCHNK = NCOL / CHUNK;        // 64 partials per row
constexpr int P1_GRID = 2048, P1_BLK = 256;
constexpr int DEPTH = 8;                   // loads in flight per wave

__global__ __launch_bounds__(P1_BLK) void chunk_sums(
    const float* __restrict__ pe, const float* __restrict__ pt,
    float* __restrict__ part, int f4_per_mat, int niter)
{
    const int gid    = blockIdx.x * P1_BLK + threadIdx.x;
    const int stride = P1_GRID * P1_BLK;
    const int lane   = threadIdx.x & 63;

    for (int i = 0; i < niter; i += DEPTH) {
        // ---- issue 8 independent coalesced 1-KiB wave loads ----
        float4 v[DEPTH];
        int    f[DEPTH];
        #pragma unroll
        for (int k = 0; k < DEPTH; ++k) {
            f[k] = gid + (i + k) * stride;
            const float* s = (f[k] < f4_per_mat)
                                 ? pe + (size_t)f[k] * 4
                                 : pt + (size_t)(f[k] - f4_per_mat) * 4;
            v[k] = *reinterpret_cast<const float4*>(s);
        }
        // ---- 8 parallel 5-level reduce chains (32-lane group = one chunk) ----
        #pragma unroll
        for (int k = 0; k < DEPTH; ++k) {
            float s = v[k].x + v[k].y + v[k].z + v[k].w;
            #pragma unroll
            for (int off = 1; off < 32; off <<= 1) s += __shfl_xor(s, off, 64);
            // lane 0 / lane 32 hold the two chunk sums of this instruction;
            // each stores its own chunk id f[k]>>5 (gid%32==0 for both).
            if ((lane & 31) == 0) part[f[k] >> 5] = s;
        }
    }
}

__global__ __launch_bounds__(512) void quantiles_from_parts(
    const float* __restrict__ pe, const float* __restrict__ pt,
    const float* __restrict__ part, float* __restrict__ out,
    int B, float inv_total)
{
    const int tid  = threadIdx.x;
    const int lane = tid & 63;
    const int wv   = tid >> 6;            // 0..7
    const int m    = wv >> 2;             // 0 = estimate, 1 = target
    const int row  = blockIdx.x * 4 + (wv & 3);
    const float* rp = (m == 0 ? pe : pt) + (size_t)row * NCOL;

    // lane's chunk partial; coalesced 256-B load
    const float p = part[((size_t)m * B + row) * NCHNK + lane];

    // wave inclusive scan
    float x = p;
    #pragma unroll
    for (int off = 1; off < 64; off <<= 1) {
        const float y = __shfl_up(x, off, 64);
        if (lane >= off) x += y;
    }
    const float incl  = x;
    float excl = __shfl_up(x, 1, 64);
    if (lane == 0) excl = 0.f;
    const float total = __shfl(x, 63, 64);

    __shared__ float sc[8][3];
    const float qs[3] = {0.25f, 0.5f, 0.75f};
    #pragma unroll
    for (int qi = 0; qi < 3; ++qi) {
        const float q = qs[qi];
        // incl_l == excl_{l+1} bitwise (same scan) -> exactly one owner;
        // lane 63 catches the rounding-only q > total clip case.
        const bool owner = (excl < q && incl >= q) || (lane == 63 && total < q);
        if (owner) {
            const float* cp = rp + (size_t)lane * CHUNK;
            float runw = excl, prev = excl, Yb = 0.f, Ya = 0.f;
            int idx = -1;
            for (int b0 = 0; b0 < CHUNK / 16 && idx < 0; ++b0) {
                float4 v[4];                       // 4 independent loads in flight
                #pragma unroll
                for (int k = 0; k < 4; ++k)
                    v[k] = *reinterpret_cast<const float4*>(cp + b0 * 16 + k * 4);
                #pragma unroll
                for (int k = 0; k < 4; ++k) {
                    const float vv[4] = {v[k].x, v[k].y, v[k].z, v[k].w};
                    #pragma unroll
                    for (int e = 0; e < 4; ++e) {
                        prev = runw; runw += vv[e];
                        if (idx < 0 && runw >= q) {
                            idx = b0 * 16 + k * 4 + e; Yb = runw; Ya = prev;
                        }
                    }
                }
            }
            // Fallback covers: (a) rounding gap between pass-1 tree sums and
            // this sequential walk, (b) q > total clip. Error <= ~1e-2, far
            // under threshold.
            if (idx < 0) { idx = CHUNK - 1; Yb = runw; Ya = prev; }
            // score = (i+1) + (q - cdf[i]) / (cdf[i] - cdf[i-1]); Ya==0 at i==0
            // (lane 0's excl is exactly 0 -> reference's (0,0) anchor).
            sc[wv][qi] = (float)(lane * CHUNK + idx + 1) + (q - Yb) / (Yb - Ya);
        }
    }
    __syncthreads();

    if (wv == 0) {
        float d = 0.f;
        if (lane < 12) {
            const int rl = lane / 3, qi = lane % 3;
            d = fabsf(sc[rl][qi] - sc[rl + 4][qi]);
        }
        #pragma unroll
        for (int off = 8; off > 0; off >>= 1) d += __shfl_down(d, off, 16);
        if (lane == 0) atomicAdd(out, d * inv_total);
    }
}

extern "C" void kernel_launch(void* const* d_in, const int* in_sizes, int n_in,
                              void* d_out, int out_size, void* d_ws, size_t ws_size,
                              hipStream_t stream) {
    const float* pe = (const float*)d_in[0];   // p_estimate
    const float* pt = (const float*)d_in[1];   // p_target
    const int B = in_sizes[0] / NCOL;
    float* part = (float*)d_ws;                // [2*B*NCHNK] = 2 MB
    const int f4_per_mat = B * NCOL / 4;
    const int niter = (2 * f4_per_mat) / (P1_GRID * P1_BLK);   // 32 for B=4096

    hipMemsetAsync(d_out, 0, sizeof(float), stream);
    chunk_sums<<<P1_GRID, P1_BLK, 0, stream>>>(pe, pt, part, f4_per_mat, niter);
    quantiles_from_parts<<<B / 4, 512, 0, stream>>>(
        pe, pt, part, (float*)d_out, B, 1.0f / (3.0f * (float)B));
}

// Round 6
// 77.430 us; speedup vs baseline: 1.1454x; 1.1454x over previous
//
#include <hip/hip_runtime.h>

// MQuantileLoss: B=4096 rows, N=8192 cols fp32.
// One 512-thread block per row: waves 0-3 handle the estimate row, waves
// 4-7 the target row. Each thread owns ONE 128-B cache line (32 floats,
// 8 independent float4 loads in flight) -- the empirically fastest memory
// structure (R1). Per-half: sequential lane sum, wave shfl-scan, cross-wave
// bases via LDS, owner threads walk 32 registers for the reference's
// piecewise-linear quantile. Pair est/tgt in-block, one atomicAdd per row.

constexpr int NCOL  = 8192;
constexpr int TPH   = 256;           // threads per half (per matrix)
constexpr int CHUNK = 32;            // elements per thread = one cache line

__global__ __launch_bounds__(512) void mq_fused(
    const float* __restrict__ pe, const float* __restrict__ pt,
    float* __restrict__ out, float inv_total)
{
    const int tid  = threadIdx.x;
    const int half = tid >> 8;        // 0 = estimate, 1 = target
    const int t    = tid & (TPH - 1); // thread-in-half
    const int lane = tid & 63;
    const int wv   = tid >> 6;        // 0..7
    const int wloc = wv & 3;          // wave-in-half
    const int row  = blockIdx.x;

    const float* rp = (half ? pt : pe) + (size_t)row * NCOL + (size_t)t * CHUNK;

    // ---- 8 independent float4 loads, all within this thread's line ----
    float v[CHUNK];
    #pragma unroll
    for (int k = 0; k < CHUNK / 4; ++k) {
        const float4 f = *reinterpret_cast<const float4*>(rp + 4 * k);
        v[4*k+0] = f.x; v[4*k+1] = f.y; v[4*k+2] = f.z; v[4*k+3] = f.w;
    }
    float lsum = 0.f;
    #pragma unroll
    for (int k = 0; k < CHUNK; ++k) lsum += v[k];   // sequential, matches walk

    // ---- wave inclusive scan of thread sums ----
    float x = lsum;
    #pragma unroll
    for (int off = 1; off < 64; off <<= 1) {
        const float y = __shfl_up(x, off, 64);
        if (lane >= off) x += y;
    }

    __shared__ float wsum[8];
    __shared__ float sbase[2][TPH + 1];   // monotone bases per half
    __shared__ float qsc[2][3];
    if (lane == 63) wsum[wv] = x;
    __syncthreads();                       // (A) wsum visible

    float wbase = 0.f;
    #pragma unroll
    for (int w = 0; w < 4; ++w) if (w < wloc) wbase += wsum[half * 4 + w];
    float excl = __shfl_up(x, 1, 64);
    if (lane == 0) excl = 0.f;
    sbase[half][t] = wbase + excl;
    if (t == TPH - 1) sbase[half][TPH] = wbase + x;  // half total
    __syncthreads();                       // (B) bases visible

    const float base  = sbase[half][t];
    const float nbase = sbase[half][t + 1];
    const float total = sbase[half][TPH];
    const float qs[3] = {0.25f, 0.5f, 0.75f};
    #pragma unroll
    for (int qi = 0; qi < 3; ++qi) {
        const float q = qs[qi];
        // sbase monotone, sbase[0]==0 < q -> exactly one owner per half;
        // last thread catches the (rounding-only) q > total clip case.
        const bool owner = (base < q && nbase >= q) ||
                           (t == TPH - 1 && total < q);
        if (owner) {
            float run = base, prev = base, Yb = 0.f, Ya = 0.f;
            int idx = -1;
            #pragma unroll
            for (int k = 0; k < CHUNK; ++k) {
                prev = run; run += v[k];
                if (idx < 0 && run >= q) { idx = k; Yb = run; Ya = prev; }
            }
            if (idx < 0) { idx = CHUNK - 1; Yb = run; Ya = prev; }  // fallback
            // score = (i+1) + (q - cdf[i]) / (cdf[i] - cdf[i-1]); Ya==0 at i==0
            // (thread 0's base is exactly 0 -> reference's (0,0) anchor).
            qsc[half][qi] = (float)(t * CHUNK + idx + 1) + (q - Yb) / (Yb - Ya);
        }
    }
    __syncthreads();                       // (C) qsc visible

    if (tid == 0) {
        const float s = fabsf(qsc[0][0] - qsc[1][0]) +
                        fabsf(qsc[0][1] - qsc[1][1]) +
                        fabsf(qsc[0][2] - qsc[1][2]);
        atomicAdd(out, s * inv_total);
    }
}

extern "C" void kernel_launch(void* const* d_in, const int* in_sizes, int n_in,
                              void* d_out, int out_size, void* d_ws, size_t ws_size,
                              hipStream_t stream) {
    const float* pe = (const float*)d_in[0];   // p_estimate
    const float* pt = (const float*)d_in[1];   // p_target
    const int B = in_sizes[0] / NCOL;
    hipMemsetAsync(d_out, 0, sizeof(float), stream);
    mq_fused<<<B, 512, 0, stream>>>(pe, pt, (float*)d_out,
                                    1.0f / (3.0f * (float)B));
}

// Round 7
// 47.136 us; speedup vs baseline: 1.8815x; 1.6427x over previous
//
#include <hip/hip_runtime.h>

// MQuantileLoss: B=4096 rows, N=8192 cols fp32.
// Kernel 1 (verbatim R1 structure, fastest measured): one 256-thread block
// per (row, matrix); thread owns 32 contiguous floats (one 128-B line,
// 8 independent float4 loads); sequential thread sum -> wave shfl-scan ->
// cross-wave bases via LDS; owner threads walk registers for the
// reference's piecewise-linear quantile. Plain stores, NO atomics.
// Kernel 2: one 1024-thread block, vectorized float4 reduce of the
// 2x[B*3] score tables -> mean |diff|. No atomics, no memset.

constexpr int BLOCK = 256;
constexpr int CHUNK = 32;          // elements per thread; BLOCK*CHUNK == NCOL
constexpr int NCOL  = 8192;

__global__ __launch_bounds__(BLOCK) void row_quantiles(
    const float* __restrict__ pe, const float* __restrict__ pt,
    float* __restrict__ qe, float* __restrict__ qt)
{
    const float* src = (blockIdx.y == 0) ? pe : pt;
    float*       dst = (blockIdx.y == 0) ? qe : qt;
    const int row = blockIdx.x;
    const int tid = threadIdx.x;
    const float* rp = src + (size_t)row * NCOL + (size_t)tid * CHUNK;

    // 8 independent float4 loads, all within this thread's cache line.
    float v[CHUNK];
    #pragma unroll
    for (int k = 0; k < CHUNK / 4; ++k) {
        const float4 f = *reinterpret_cast<const float4*>(rp + 4 * k);
        v[4*k+0] = f.x; v[4*k+1] = f.y; v[4*k+2] = f.z; v[4*k+3] = f.w;
    }
    float lsum = 0.f;
    #pragma unroll
    for (int k = 0; k < CHUNK; ++k) lsum += v[k];   // sequential, matches walk

    // Block exclusive scan of chunk sums.
    const int lane = tid & 63, wave = tid >> 6;
    float x = lsum;                       // wave inclusive scan
    #pragma unroll
    for (int off = 1; off < 64; off <<= 1) {
        const float y = __shfl_up(x, off, 64);
        if (lane >= off) x += y;
    }
    __shared__ float wsum[4];
    __shared__ float sbase[BLOCK + 1];    // monotone CDF bases, sbase[BLOCK]=total
    __shared__ float qscore[3];
    if (lane == 63) wsum[wave] = x;
    __syncthreads();
    float wbase = 0.f;
    #pragma unroll
    for (int w = 0; w < 4; ++w) if (w < wave) wbase += wsum[w];
    float excl = __shfl_up(x, 1, 64);
    if (lane == 0) excl = 0.f;
    sbase[tid] = wbase + excl;
    if (tid == BLOCK - 1) sbase[BLOCK] = wbase + x;
    __syncthreads();

    const float base  = sbase[tid];
    const float nbase = sbase[tid + 1];
    const float qs[3] = {0.25f, 0.5f, 0.75f};
    #pragma unroll
    for (int qi = 0; qi < 3; ++qi) {
        const float q = qs[qi];
        // sbase monotone, sbase[0]==0 < q -> exactly one owner;
        // last thread catches the (rounding-only) q > total clip case.
        const bool owner = (base < q && nbase >= q) ||
                           (tid == BLOCK - 1 && nbase < q);
        if (owner) {
            float run = base, prev = base, Yb = 0.f, Ya = 0.f;
            int idx = -1;
            #pragma unroll
            for (int k = 0; k < CHUNK; ++k) {
                prev = run; run += v[k];
                if (idx < 0 && run >= q) { idx = k; Yb = run; Ya = prev; }
            }
            if (idx < 0) { idx = CHUNK - 1; Yb = run; Ya = prev; }  // fallback
            // score = (i+1) + (q - cdf[i]) / (cdf[i] - cdf[i-1]); Ya==0 at i==0.
            qscore[qi] = (float)(tid * CHUNK + idx + 1) + (q - Yb) / (Yb - Ya);
        }
    }
    __syncthreads();
    if (tid < 3) dst[row * 3 + tid] = qscore[tid];
}

// n4 = (B*3)/4 float4 elements per table; B*3 = 12288 -> n4 = 3072.
__global__ __launch_bounds__(1024) void reduce_absdiff(
    const float* __restrict__ qe, const float* __restrict__ qt,
    float* __restrict__ out, int n4, float inv_n)
{
    const int tid = threadIdx.x;
    const float4* a = reinterpret_cast<const float4*>(qe);
    const float4* b = reinterpret_cast<const float4*>(qt);
    float s = 0.f;
    #pragma unroll
    for (int k = 0; k < 3; ++k) {            // 3072 / 1024 = 3 float4 each
        const int i = tid + k * 1024;
        if (i < n4) {
            const float4 va = a[i], vb = b[i];
            s += fabsf(va.x - vb.x) + fabsf(va.y - vb.y) +
                 fabsf(va.z - vb.z) + fabsf(va.w - vb.w);
        }
    }
    #pragma unroll
    for (int off = 32; off > 0; off >>= 1) s += __shfl_down(s, off, 64);
    __shared__ float ws[16];
    const int lane = tid & 63, wv = tid >> 6;
    if (lane == 0) ws[wv] = s;
    __syncthreads();
    if (wv == 0) {
        float t = (lane < 16) ? ws[lane] : 0.f;
        #pragma unroll
        for (int off = 8; off > 0; off >>= 1) t += __shfl_down(t, off, 64);
        if (lane == 0) out[0] = t * inv_n;
    }
}

extern "C" void kernel_launch(void* const* d_in, const int* in_sizes, int n_in,
                              void* d_out, int out_size, void* d_ws, size_t ws_size,
                              hipStream_t stream) {
    const float* pe = (const float*)d_in[0];   // p_estimate
    const float* pt = (const float*)d_in[1];   // p_target
    const int B = in_sizes[0] / NCOL;
    float* qe = (float*)d_ws;                  // [B*3]
    float* qt = qe + (size_t)B * 3;            // [B*3]
    dim3 grid(B, 2);
    row_quantiles<<<grid, BLOCK, 0, stream>>>(pe, pt, qe, qt);
    reduce_absdiff<<<1, 1024, 0, stream>>>(qe, qt, (float*)d_out,
                                           (B * 3) / 4, 1.0f / (3.0f * (float)B));
}